// Round 1
// baseline (83.610 us; speedup 1.0000x reference)
//
#include <hip/hip_runtime.h>

// Ray-sphere intersection: N rays x 64 moving spheres -> closest hit distance.
// x: (1, N, 7) f32 = [origin(3), t_ray(1), direction(3)]
// z: (1, 384) f32 = 64 spheres x [center(3), velocity(3)]
// out: mu (N) ++ sigma (N), f32

constexpr int NSPH = 64;

__global__ __launch_bounds__(256) void ray_sphere_kernel(
    const float* __restrict__ x, const float* __restrict__ z,
    float* __restrict__ out, int N)
{
    int n = blockIdx.x * 256 + threadIdx.x;
    if (n >= N) return;

    const float* xr = x + (long)n * 7;
    float ox = xr[0], oy = xr[1], oz = xr[2];
    float t  = xr[3];
    float dx = xr[4], dy = xr[5], dz = xr[6];

    float inv = 1.0f / (sqrtf(fmaf(dx, dx, fmaf(dy, dy, dz * dz))) + 1e-12f);
    dx *= inv; dy *= inv; dz *= inv;

    float closest = 1e10f;  // BIG

    #pragma unroll 16
    for (int s = 0; s < NSPH; ++s) {
        const float* zs = z + s * 6;   // uniform index -> scalar loads
        float ocx = fmaf(zs[3], t, zs[0]) - ox;
        float ocy = fmaf(zs[4], t, zs[1]) - oy;
        float ocz = fmaf(zs[5], t, zs[2]) - oz;

        float b    = fmaf(dx, ocx, fmaf(dy, ocy, dz * ocz));
        float csq  = fmaf(ocx, ocx, fmaf(ocy, ocy, ocz * ocz));
        float disc = fmaf(b, b, 1.0f - csq);   // b^2 - (|oc|^2 - R^2), R=1

        // Match reference exactly: sqrt(disc>0 ? disc : 1.0)
        float sq = sqrtf(disc > 0.0f ? disc : 1.0f);
        float t0 = b - sq;
        float t1 = b + sq;
        float th = (t0 > 0.0f) ? t0 : t1;

        bool valid = (disc >= 0.0f) && (t1 > 0.0f);
        float dist = valid ? th : 1e10f;
        closest = fminf(closest, dist);
    }

    out[n]     = closest;   // mu
    out[N + n] = 0.002f;    // sigma (DISTANCE_ERROR)
}

extern "C" void kernel_launch(void* const* d_in, const int* in_sizes, int n_in,
                              void* d_out, int out_size, void* d_ws, size_t ws_size,
                              hipStream_t stream) {
    const float* x = (const float*)d_in[0];
    const float* z = (const float*)d_in[1];
    float* out = (float*)d_out;
    int N = in_sizes[0] / 7;   // 1048576

    int blocks = (N + 255) / 256;
    ray_sphere_kernel<<<blocks, 256, 0, stream>>>(x, z, out, N);
}

// Round 2
// 39.514 us; speedup vs baseline: 2.1160x; 2.1160x over previous
//
#include <hip/hip_runtime.h>

// Ray-sphere intersection: N rays x 64 moving spheres -> closest hit distance.
// x: (1, N, 7) f32 = [origin(3), t_ray(1), direction(3)]
// z: (1, 384) f32 = 64 spheres x [center(3), velocity(3)]
// out: mu (N) ++ sigma (N), f32
//
// 2 rays per thread via ext_vector_type(2) so the FMA-dense part maps to
// v_pk_fma_f32 (packed fp32, 2x rate). Tail (sqrt/selects/min) is scalar
// per component. Hardware v_sqrt_f32/v_rcp_f32 via builtins (~1 ULP,
// threshold here is ~2e8 so approximation error is irrelevant).

typedef float v2f __attribute__((ext_vector_type(2)));

constexpr int NSPH = 64;
constexpr float BIGF = 1e10f;

__device__ __forceinline__ v2f s2(float f) { return (v2f){f, f}; }

__global__ __launch_bounds__(256) void ray_sphere_kernel(
    const float* __restrict__ x, const float* __restrict__ z,
    float* __restrict__ out, int N)
{
    int pair = blockIdx.x * 256 + threadIdx.x;
    int n0 = pair * 2;                 // this thread handles rays n0, n0+1
    if (n0 >= N) return;

    const float* xr = x + (long)n0 * 7;
    v2f ox = {xr[0], xr[7]};
    v2f oy = {xr[1], xr[8]};
    v2f oz = {xr[2], xr[9]};
    v2f t  = {xr[3], xr[10]};
    v2f dx = {xr[4], xr[11]};
    v2f dy = {xr[5], xr[12]};
    v2f dz = {xr[6], xr[13]};

    // normalize d:  d / (sqrt(|d|^2) + 1e-12)
    v2f n2 = __builtin_elementwise_fma(dx, dx,
             __builtin_elementwise_fma(dy, dy, dz * dz));
    v2f inv;
    inv[0] = __builtin_amdgcn_rcpf(__builtin_amdgcn_sqrtf(n2[0]) + 1e-12f);
    inv[1] = __builtin_amdgcn_rcpf(__builtin_amdgcn_sqrtf(n2[1]) + 1e-12f);
    dx *= inv; dy *= inv; dz *= inv;

    v2f closest = {BIGF, BIGF};

    #pragma unroll 8
    for (int s = 0; s < NSPH; ++s) {
        const float* zs = z + s * 6;   // uniform -> scalar loads (constant cache)
        float cx = zs[0], cy = zs[1], cz = zs[2];
        float vx = zs[3], vy = zs[4], vz = zs[5];

        // oc = (c - o) + v * t          (3 pk_sub + 3 pk_fma)
        v2f ocx = __builtin_elementwise_fma(s2(vx), t, cx - ox);
        v2f ocy = __builtin_elementwise_fma(s2(vy), t, cy - oy);
        v2f ocz = __builtin_elementwise_fma(s2(vz), t, cz - oz);

        // b = d . oc                    (1 pk_mul + 2 pk_fma)
        v2f b = __builtin_elementwise_fma(dx, ocx,
                __builtin_elementwise_fma(dy, ocy, dz * ocz));
        // |oc|^2                        (1 pk_mul + 2 pk_fma)
        v2f csq = __builtin_elementwise_fma(ocx, ocx,
                  __builtin_elementwise_fma(ocy, ocy, ocz * ocz));
        // disc = b^2 - (|oc|^2 - 1)     (1 pk_sub + 1 pk_fma)
        v2f disc = __builtin_elementwise_fma(b, b, 1.0f - csq);

        // scalar tail per ray
        #pragma unroll
        for (int k = 0; k < 2; ++k) {
            float d  = disc[k];
            float bb = b[k];
            float sq = __builtin_amdgcn_sqrtf(d > 0.0f ? d : 1.0f);  // ref quirk: sqrt(1) when disc<=0
            // t_hit = t0>0 ? t0 : t1 ;  t0>0 <=> b>sq ; t1 = b+sq
            float ssel = (bb > sq) ? -sq : sq;
            float th   = bb + ssel;
            // valid = disc>=0 && t1>0 ;  t1>0 <=> b > -sq
            bool valid = (d >= 0.0f) & (bb > -sq);
            float dist = valid ? th : BIGF;
            closest[k] = fminf(closest[k], dist);
        }
    }

    // mu, then sigma; n0 and N are even -> 8B-aligned float2 stores
    *(v2f*)(out + n0) = closest;
    *(v2f*)(out + N + n0) = (v2f){0.002f, 0.002f};
}

extern "C" void kernel_launch(void* const* d_in, const int* in_sizes, int n_in,
                              void* d_out, int out_size, void* d_ws, size_t ws_size,
                              hipStream_t stream) {
    const float* x = (const float*)d_in[0];
    const float* z = (const float*)d_in[1];
    float* out = (float*)d_out;
    int N = in_sizes[0] / 7;   // 1048576

    int pairs = N / 2;
    int blocks = (pairs + 255) / 256;
    ray_sphere_kernel<<<blocks, 256, 0, stream>>>(x, z, out, N);
}

// Round 3
// 34.612 us; speedup vs baseline: 2.4157x; 1.1416x over previous
//
#include <hip/hip_runtime.h>

// Ray-sphere intersection: N rays x 64 moving spheres -> closest hit distance.
// x: (1, N, 7) f32 = [origin(3), t_ray(1), direction(3)]
// z: (1, 384) f32 = 64 spheres x [center(3), velocity(3)]
// out: mu (N) ++ sigma (N), f32
//
// 2 rays per thread, ext_vector_type(2) -> v_pk_{fma,add,mul}_f32 for all the
// pairwise math. Tail uses raw v_sqrt_f32: disc<0 -> NaN -> all ordered
// compares false -> falls through to BIG, which replaces the explicit
// disc>=0 gate and the pre-sqrt select. (Only divergence from the reference
// is disc == 0.0f exactly, a measure-zero fp32 event; threshold here is 2e8.)

typedef float v2f __attribute__((ext_vector_type(2)));

constexpr int NSPH = 64;
constexpr float BIGF = 1e10f;

__global__ __launch_bounds__(256, 8) void ray_sphere_kernel(
    const float* __restrict__ x, const float* __restrict__ z,
    float* __restrict__ out, int N)
{
    int pair = blockIdx.x * 256 + threadIdx.x;
    int n0 = pair * 2;                 // this thread handles rays n0, n0+1
    if (n0 >= N) return;

    const float* xr = x + (long)n0 * 7;
    v2f ox = {xr[0], xr[7]};
    v2f oy = {xr[1], xr[8]};
    v2f oz = {xr[2], xr[9]};
    v2f t  = {xr[3], xr[10]};
    v2f dx = {xr[4], xr[11]};
    v2f dy = {xr[5], xr[12]};
    v2f dz = {xr[6], xr[13]};

    // normalize d:  d / (sqrt(|d|^2) + 1e-12)
    v2f n2 = __builtin_elementwise_fma(dx, dx,
             __builtin_elementwise_fma(dy, dy, dz * dz));
    v2f inv;
    inv[0] = __builtin_amdgcn_rcpf(__builtin_amdgcn_sqrtf(n2[0]) + 1e-12f);
    inv[1] = __builtin_amdgcn_rcpf(__builtin_amdgcn_sqrtf(n2[1]) + 1e-12f);
    dx *= inv; dy *= inv; dz *= inv;

    v2f closest = {BIGF, BIGF};

    #pragma unroll 16
    for (int s = 0; s < NSPH; ++s) {
        const float* zs = z + s * 6;   // uniform -> s_load, broadcast via SGPR
        float cx = zs[0], cy = zs[1], cz = zs[2];
        float vx = zs[3], vy = zs[4], vz = zs[5];

        // oc = (c - o) + v * t          (3 pk_sub + 3 pk_fma)
        v2f ocx = __builtin_elementwise_fma((v2f){vx, vx}, t, cx - ox);
        v2f ocy = __builtin_elementwise_fma((v2f){vy, vy}, t, cy - oy);
        v2f ocz = __builtin_elementwise_fma((v2f){vz, vz}, t, cz - oz);

        // b = d . oc                    (1 pk_mul + 2 pk_fma)
        v2f b = __builtin_elementwise_fma(dx, ocx,
                __builtin_elementwise_fma(dy, ocy, dz * ocz));
        // |oc|^2                        (1 pk_mul + 2 pk_fma)
        v2f csq = __builtin_elementwise_fma(ocx, ocx,
                  __builtin_elementwise_fma(ocy, ocy, ocz * ocz));
        // disc = b^2 - (|oc|^2 - 1)     (1 pk_sub + 1 pk_fma)
        v2f disc = __builtin_elementwise_fma(b, b, 1.0f - csq);

        // sq = sqrt(disc); disc<0 -> NaN -> both compares false -> BIG
        v2f sq;
        sq[0] = __builtin_amdgcn_sqrtf(disc[0]);
        sq[1] = __builtin_amdgcn_sqrtf(disc[1]);

        v2f t0 = b - sq;   // pk_add with neg
        v2f t1 = b + sq;   // pk_add

        #pragma unroll
        for (int k = 0; k < 2; ++k) {
            float r1 = (t1[k] > 0.0f) ? t1[k] : BIGF;   // cmp + cndmask
            float r  = (t0[k] > 0.0f) ? t0[k] : r1;     // cmp + cndmask
            closest[k] = fminf(closest[k], r);          // v_min
        }
    }

    // mu, then sigma; n0 and N are even -> 8B-aligned float2 stores
    *(v2f*)(out + n0) = closest;
    *(v2f*)(out + N + n0) = (v2f){0.002f, 0.002f};
}

extern "C" void kernel_launch(void* const* d_in, const int* in_sizes, int n_in,
                              void* d_out, int out_size, void* d_ws, size_t ws_size,
                              hipStream_t stream) {
    const float* x = (const float*)d_in[0];
    const float* z = (const float*)d_in[1];
    float* out = (float*)d_out;
    int N = in_sizes[0] / 7;   // 1048576

    int pairs = N / 2;
    int blocks = (pairs + 255) / 256;
    ray_sphere_kernel<<<blocks, 256, 0, stream>>>(x, z, out, N);
}